// Round 7
// baseline (1196.985 us; speedup 1.0000x reference)
//
#include <hip/hip_runtime.h>
#include <hip/hip_bf16.h>
#include <math.h>

// Problem constants
#define B    2
#define CIN  64
#define LIN  8192
#define L    2048
#define D    128
#define DI   256
#define NS   16
#define RK   8
#define NSTREAM 4       // (dir, batch): s = dir*2 + b
#define CHUNK 16
#define NC   (L/CHUNK)  // 128
#define TOK  (NSTREAM*L) // 8192 token-rows
#define NFLAGS (3*NSTREAM*NC)

typedef short  bfrag __attribute__((ext_vector_type(8)));  // 8 bf16 (4 VGPRs)
typedef float  facc  __attribute__((ext_vector_type(4)));  // 4 fp32 acc

__device__ __forceinline__ float sigmoidf_(float x){ return 1.f/(1.f+__expf(-x)); }
__device__ __forceinline__ float siluf_(float x){ return x*sigmoidf_(x); }
__device__ __forceinline__ ushort f2bf(float f){
    unsigned u = __float_as_uint(f);
    u += 0x7fffu + ((u>>16)&1u);       // round-to-nearest-even
    return (ushort)(u>>16);
}
__device__ __forceinline__ float softplusf_(float t){
    return (t > 20.f) ? t : __logf(1.f + __expf(t));
}

// ---------------- weight conversion + flag zeroing (ws is poisoned every launch)
// dst layout: wbd(32768) | wbi(393216) | wbo(196608) | wbx(98304, 40->64 pad)
__global__ void k_cvtall(const float* __restrict__ cw, const float* __restrict__ ipw,
                         const float* __restrict__ opw, const float* __restrict__ xpw,
                         ushort* __restrict__ dst, int* __restrict__ flags){
    int i = blockIdx.x*256 + threadIdx.x;   // 720896 total
    if (i < NFLAGS) flags[i] = 0;
    ushort v;
    if (i < 32768)       v = f2bf(cw[i]);
    else if (i < 425984) v = f2bf(ipw[i-32768]);
    else if (i < 622592) v = f2bf(opw[i-425984]);
    else {
        int t = i - 622592;
        int k = t & 255, nr = (t>>8) & 63, j = t>>14;
        v = (nr < 40) ? f2bf(xpw[((size_t)j*40 + nr)*256 + k]) : (ushort)0;
    }
    dst[i] = v;
}

// ---------------- FUSED patch-pack + downsample GEMM + bias + silu, dual write
// grid (64, 2), block 256: 64 tokens x 64 cols per block
__global__ void k_down(const float* __restrict__ x, const ushort* __restrict__ wd,
                       const float* __restrict__ bias, float* __restrict__ h){
    __shared__ ushort sxd[64*264];   // 64 tokens x 256 bf16, row stride 264
    int tid = threadIdx.x;
    int m0 = blockIdx.x*64;          // token in (b*L+l) space
    int b = m0 >> 11;
    int l0 = m0 & 2047;
    for (int idx = tid; idx < 64*64; idx += 256){
        int t = idx & 63, cc = idx >> 6;
        float4 v = *(const float4*)(x + ((size_t)(b*CIN + cc))*LIN + 4*(l0+t));
        ushort4 o; o.x=f2bf(v.x); o.y=f2bf(v.y); o.z=f2bf(v.z); o.w=f2bf(v.w);
        *(ushort4*)&sxd[t*264 + cc*4] = o;
    }
    __syncthreads();
    int w = tid>>6, lane = tid&63, rw = w>>1, cw = w&1;
    int q = lane>>4, r = lane&15;
    int n0 = blockIdx.y*64 + cw*32;
    const ushort* b0p = wd + (size_t)(n0 + r)*256 + q*8;
    const ushort* b1p = b0p + (size_t)16*256;
    facc acc[2][2] = {};
    #pragma unroll
    for (int kb=0; kb<8; ++kb){
        bfrag a0 = *(bfrag*)&sxd[(rw*32 + r)*264 + kb*32 + q*8];
        bfrag a1 = *(bfrag*)&sxd[(rw*32 + 16 + r)*264 + kb*32 + q*8];
        bfrag b0 = *(const bfrag*)(b0p + kb*32);
        bfrag b1 = *(const bfrag*)(b1p + kb*32);
        acc[0][0] = __builtin_amdgcn_mfma_f32_16x16x32_bf16(a0,b0,acc[0][0],0,0,0);
        acc[0][1] = __builtin_amdgcn_mfma_f32_16x16x32_bf16(a0,b1,acc[0][1],0,0,0);
        acc[1][0] = __builtin_amdgcn_mfma_f32_16x16x32_bf16(a1,b0,acc[1][0],0,0,0);
        acc[1][1] = __builtin_amdgcn_mfma_f32_16x16x32_bf16(a1,b1,acc[1][1],0,0,0);
    }
    #pragma unroll
    for (int im=0; im<2; ++im)
    #pragma unroll
    for (int in=0; in<2; ++in){
        int col = n0 + in*16 + r;
        float bv = bias[col];
        #pragma unroll
        for (int r2=0; r2<4; ++r2){
            int row = m0 + rw*32 + im*16 + q*4 + r2;
            int bb = row >> 11, l = row & 2047;
            float v = siluf_(acc[im][in][r2] + bv);
            h[((size_t)(bb*L + l))*D + col] = v;
            h[((size_t)((2+bb)*L + (L-1-l)))*D + col] = v;
        }
    }
}

// ---------------- FUSED residual+LN+in_proj GEMM
// grid (TOK/64, 8), block 256; only y==0 persists res (ping-pong).
__global__ void k_fused_in(const float* __restrict__ curIn, const float* __restrict__ resIn,
                           float* __restrict__ resOut,
                           const float* __restrict__ lnw, const float* __restrict__ lnb,
                           const ushort* __restrict__ wbi,
                           float* __restrict__ xm, float* __restrict__ z, int blk, int first){
    __shared__ ushort sh[64*136];   // 64 tokens x 128 bf16, row stride 136
    int m0 = blockIdx.x*64;
    int s = m0 >> 11; int j = (s>>1)*3 + blk;
    int tid = threadIdx.x;
    int t = tid >> 2, sub = tid & 3;
    size_t rowoff = (size_t)(m0 + t)*D + sub*32;
    float4 v[8];
    const float4* cp = (const float4*)(curIn + rowoff);
    #pragma unroll
    for (int i=0;i<8;++i) v[i] = cp[i];
    if (!first){
        const float4* rp = (const float4*)(resIn + rowoff);
        #pragma unroll
        for (int i=0;i<8;++i){ float4 rv = rp[i]; v[i].x+=rv.x; v[i].y+=rv.y; v[i].z+=rv.z; v[i].w+=rv.w; }
    }
    if (blockIdx.y == 0){
        float4* ro = (float4*)(resOut + rowoff);
        #pragma unroll
        for (int i=0;i<8;++i) ro[i] = v[i];
    }
    float s1 = 0.f, s2 = 0.f;
    #pragma unroll
    for (int i=0;i<8;++i){
        s1 += v[i].x + v[i].y + v[i].z + v[i].w;
        s2 += v[i].x*v[i].x + v[i].y*v[i].y + v[i].z*v[i].z + v[i].w*v[i].w;
    }
    s1 += __shfl_xor(s1, 1); s2 += __shfl_xor(s2, 1);
    s1 += __shfl_xor(s1, 2); s2 += __shfl_xor(s2, 2);
    float mean = s1*(1.f/128.f);
    float var  = s2*(1.f/128.f) - mean*mean;
    float rstd = rsqrtf(var + 1e-5f);
    const float4* lwp = (const float4*)(lnw + j*D + sub*32);
    const float4* lbp = (const float4*)(lnb + j*D + sub*32);
    #pragma unroll
    for (int i=0;i<8;++i){
        float4 lw = lwp[i], lb = lbp[i];
        ushort4 o;
        o.x = f2bf((v[i].x-mean)*rstd*lw.x + lb.x);
        o.y = f2bf((v[i].y-mean)*rstd*lw.y + lb.y);
        o.z = f2bf((v[i].z-mean)*rstd*lw.z + lb.z);
        o.w = f2bf((v[i].w-mean)*rstd*lw.w + lb.w);
        *(ushort4*)&sh[t*136 + sub*32 + i*4] = o;
    }
    __syncthreads();
    int w = tid>>6, lane = tid&63, rw = w>>1, cw = w&1;
    int q = lane>>4, r = lane&15;
    int n0 = blockIdx.y*64 + cw*32;
    const ushort* b0p = wbi + ((size_t)j*512 + n0 + r)*128 + q*8;
    const ushort* b1p = b0p + (size_t)16*128;
    facc acc[2][2] = {};
    #pragma unroll
    for (int kb=0; kb<4; ++kb){
        bfrag a0 = *(bfrag*)&sh[(rw*32 + r)*136 + kb*32 + q*8];
        bfrag a1 = *(bfrag*)&sh[(rw*32 + 16 + r)*136 + kb*32 + q*8];
        bfrag b0 = *(const bfrag*)(b0p + kb*32);
        bfrag b1 = *(const bfrag*)(b1p + kb*32);
        acc[0][0] = __builtin_amdgcn_mfma_f32_16x16x32_bf16(a0,b0,acc[0][0],0,0,0);
        acc[0][1] = __builtin_amdgcn_mfma_f32_16x16x32_bf16(a0,b1,acc[0][1],0,0,0);
        acc[1][0] = __builtin_amdgcn_mfma_f32_16x16x32_bf16(a1,b0,acc[1][0],0,0,0);
        acc[1][1] = __builtin_amdgcn_mfma_f32_16x16x32_bf16(a1,b1,acc[1][1],0,0,0);
    }
    #pragma unroll
    for (int im=0; im<2; ++im)
    #pragma unroll
    for (int in=0; in<2; ++in){
        int e = n0 + in*16 + r;
        #pragma unroll
        for (int r2=0; r2<4; ++r2){
            int row = m0 + rw*32 + im*16 + q*4 + r2;
            float vv = acc[im][in][r2];
            if (e < DI) xm[(size_t)row*DI + e] = vv;
            else        z [(size_t)row*DI + (e-DI)] = vv;
        }
    }
}

// ---------------- MEGA: conv+silu -> xproj GEMM -> dtproj -> single-pass scan
// (decoupled look-back) -> gate -> out_proj GEMM
// grid (NC, NSTREAM), block 256 (d)
__global__ void k_mega(const float* __restrict__ xm, const float* __restrict__ z,
                       const float* __restrict__ cw, const float* __restrict__ cb,
                       const ushort* __restrict__ wbx,
                       const float* __restrict__ Wdt, const float* __restrict__ bdt,
                       const float* __restrict__ A_log, const float* __restrict__ Dp,
                       const ushort* __restrict__ wbo,
                       float* __restrict__ Apub, float* __restrict__ Bpub,
                       float* __restrict__ Ppub, int* __restrict__ flags,
                       float* __restrict__ cur, int blk){
    int c = blockIdx.x, s = blockIdx.y; int j = (s>>1)*3 + blk;
    int d = threadIdx.x;
    __shared__ ushort sx[CHUNK*264];   // conv output bf16; reused as gate output
    __shared__ float sdbc[CHUNK*68];   // xproj output: 16 tokens x 40 (pad 68)
    __shared__ int sflag;
    int base_tok = s*L + c*CHUNK;

    // Phase 0: causal conv + silu (rolling registers)
    const float* w4 = cw + ((size_t)j*DI + d)*4;
    float cw0=w4[0], cw1=w4[1], cw2=w4[2], cw3=w4[3];
    float cbb = cb[j*DI + d];
    float xm1=0.f, xm2=0.f, xm3=0.f;
    if (c > 0){
        xm1 = xm[(size_t)(base_tok-1)*DI + d];
        xm2 = xm[(size_t)(base_tok-2)*DI + d];
        xm3 = xm[(size_t)(base_tok-3)*DI + d];
    }
    float xv[CHUNK];
    #pragma unroll
    for (int i=0;i<CHUNK;++i){
        float x0 = xm[(size_t)(base_tok+i)*DI + d];
        float v = siluf_(cbb + cw3*x0 + cw2*xm1 + cw1*xm2 + cw0*xm3);
        xv[i] = v;
        sx[i*264 + d] = f2bf(v);
        xm3 = xm2; xm2 = xm1; xm1 = x0;
    }
    __syncthreads();

    // Phase 1: xproj GEMM 16x64, K=256
    {
        int w = d>>6, lane = d&63, q = lane>>4, r = lane&15;
        facc acc = {};
        const ushort* bp = wbx + ((size_t)j*64 + w*16 + r)*256 + q*8;
        #pragma unroll
        for (int kb=0; kb<8; ++kb){
            bfrag a = *(bfrag*)&sx[r*264 + kb*32 + q*8];
            bfrag b = *(const bfrag*)(bp + kb*32);
            acc = __builtin_amdgcn_mfma_f32_16x16x32_bf16(a,b,acc,0,0,0);
        }
        #pragma unroll
        for (int r2=0; r2<4; ++r2)
            sdbc[(q*4+r2)*68 + w*16 + r] = acc[r2];
    }
    __syncthreads();

    // per-d params
    float A[NS];
    const float* ar = A_log + ((size_t)j*DI + d)*NS;
    #pragma unroll
    for (int n=0;n<NS;++n) A[n] = -__expf(ar[n]);
    float wv[RK];
    const float* wr = Wdt + ((size_t)j*DI + d)*RK;
    #pragma unroll
    for (int r=0;r<RK;++r) wv[r] = wr[r];
    float bb2 = bdt[j*DI + d];
    float Dpd = Dp[j*DI + d];

    // Phase 2: local scan summary
    float ap[NS], hs[NS];
    #pragma unroll
    for (int n=0;n<NS;++n){ ap[n]=1.f; hs[n]=0.f; }
    #pragma unroll
    for (int l=0;l<CHUNK;++l){
        float t = bb2;
        #pragma unroll
        for (int r=0;r<RK;++r) t += sdbc[l*68+r]*wv[r];
        float dtv = softplusf_(t);
        float dbx = dtv*xv[l];
        #pragma unroll
        for (int n=0;n<NS;++n){
            float dA = __expf(dtv*A[n]);
            ap[n] *= dA;
            hs[n] = dA*hs[n] + dbx*sdbc[l*68+8+n];
        }
    }

    // Phase 3: publish + look-back (decoupled, CUB-style)
    size_t pbase = ((size_t)(s*NC + c)*NS)*DI + d;
    int fbase = s*NC;
    if (c == 0){
        #pragma unroll
        for (int n=0;n<NS;++n) Ppub[pbase + (size_t)n*DI] = hs[n];
        __threadfence();
        __syncthreads();
        if (d == 0) __hip_atomic_store(&flags[fbase], 2, __ATOMIC_RELEASE, __HIP_MEMORY_SCOPE_AGENT);
        #pragma unroll
        for (int n=0;n<NS;++n) hs[n] = 0.f;     // h0
    } else {
        #pragma unroll
        for (int n=0;n<NS;++n){
            Apub[pbase + (size_t)n*DI] = ap[n];
            Bpub[pbase + (size_t)n*DI] = hs[n];
        }
        __threadfence();
        __syncthreads();
        if (d == 0) __hip_atomic_store(&flags[fbase+c], 1, __ATOMIC_RELEASE, __HIP_MEMORY_SCOPE_AGENT);
        float accA[NS], accB[NS];
        #pragma unroll
        for (int n=0;n<NS;++n){ accA[n]=1.f; accB[n]=0.f; }
        int k = c-1;
        for (;;){
            if (d == 0){
                int ff;
                do { ff = __hip_atomic_load(&flags[fbase+k], __ATOMIC_ACQUIRE, __HIP_MEMORY_SCOPE_AGENT); } while (ff == 0);
                sflag = ff;
            }
            __syncthreads();
            int f = sflag;
            size_t kb2 = ((size_t)(s*NC + k)*NS)*DI + d;
            if (f == 2){
                #pragma unroll
                for (int n=0;n<NS;++n) accB[n] += accA[n]*Ppub[kb2 + (size_t)n*DI];
            } else {
                #pragma unroll
                for (int n=0;n<NS;++n){
                    accB[n] += accA[n]*Bpub[kb2 + (size_t)n*DI];
                    accA[n] *= Apub[kb2 + (size_t)n*DI];
                }
            }
            __syncthreads();
            if (f == 2) break;
            --k;
        }
        // publish inclusive P = ap*h0 + hs; then hs := h0
        #pragma unroll
        for (int n=0;n<NS;++n) Ppub[pbase + (size_t)n*DI] = ap[n]*accB[n] + hs[n];
        __threadfence();
        __syncthreads();
        if (d == 0) __hip_atomic_store(&flags[fbase+c], 2, __ATOMIC_RELEASE, __HIP_MEMORY_SCOPE_AGENT);
        #pragma unroll
        for (int n=0;n<NS;++n) hs[n] = accB[n];
    }

    // Phase 4: final scan with carry-in, gate -> sx (as bf16 g)
    #pragma unroll
    for (int l=0;l<CHUNK;++l){
        float t = bb2;
        #pragma unroll
        for (int r=0;r<RK;++r) t += sdbc[l*68+r]*wv[r];
        float dtv = softplusf_(t);
        float dbx = dtv*xv[l];
        float p = 0.f;
        #pragma unroll
        for (int n=0;n<NS;++n){
            float dA = __expf(dtv*A[n]);
            hs[n] = dA*hs[n] + dbx*sdbc[l*68+8+n];
            p += hs[n]*sdbc[l*68+24+n];
        }
        float zv = z[(size_t)(base_tok+l)*DI + d];
        sx[l*264 + d] = f2bf((p + Dpd*xv[l])*siluf_(zv));
    }
    __syncthreads();

    // Phase 5: out_proj GEMM 16x128, K=256 -> cur
    {
        int w = d>>6, lane = d&63, q = lane>>4, r = lane&15;
        int n0 = w*32;
        facc acc[2] = {};
        const ushort* b0p = wbo + ((size_t)j*128 + n0 + r)*256 + q*8;
        const ushort* b1p = b0p + (size_t)16*256;
        #pragma unroll
        for (int kb=0; kb<8; ++kb){
            bfrag a  = *(bfrag*)&sx[r*264 + kb*32 + q*8];
            bfrag b0 = *(const bfrag*)(b0p + kb*32);
            bfrag b1 = *(const bfrag*)(b1p + kb*32);
            acc[0] = __builtin_amdgcn_mfma_f32_16x16x32_bf16(a,b0,acc[0],0,0,0);
            acc[1] = __builtin_amdgcn_mfma_f32_16x16x32_bf16(a,b1,acc[1],0,0,0);
        }
        #pragma unroll
        for (int in=0; in<2; ++in){
            int col = n0 + in*16 + r;
            #pragma unroll
            for (int r2=0; r2<4; ++r2){
                int row = q*4 + r2;
                cur[(size_t)(base_tok+row)*D + col] = acc[in][r2];
            }
        }
    }
}

// ---------------- final combine
__global__ void k_final(const float* __restrict__ cur, const float* __restrict__ res,
                        float* __restrict__ out){
    int l = blockIdx.x, b = blockIdx.y, d = threadIdx.x;
    int tf = (b*L + l)*D + d;
    int tbk = ((2+b)*L + (L-1-l))*D + d;
    float f  = cur[tf] + res[tf];
    float bw = cur[tbk] + res[tbk];
    out[((size_t)(b*D + d))*L + l] = f + bw;
    out[(size_t)2*D*L + (size_t)(b*L + l)*D + d] = res[tf];
    out[(size_t)2*D*L + (size_t)((2+b)*L + l)*D + d] = res[((2+b)*L + l)*D + d];
}

extern "C" void kernel_launch(void* const* d_in, const int* in_sizes, int n_in,
                              void* d_out, int out_size, void* d_ws, size_t ws_size,
                              hipStream_t stream){
    const float* x         = (const float*)d_in[0];
    const float* convd_w   = (const float*)d_in[1];
    const float* convd_b   = (const float*)d_in[2];
    const float* ln_w      = (const float*)d_in[3];
    const float* ln_b      = (const float*)d_in[4];
    const float* in_proj_w = (const float*)d_in[5];
    const float* conv_w    = (const float*)d_in[6];
    const float* conv_b    = (const float*)d_in[7];
    const float* xproj_w   = (const float*)d_in[8];
    const float* dtproj_w  = (const float*)d_in[9];
    const float* dtproj_b  = (const float*)d_in[10];
    const float* A_log     = (const float*)d_in[11];
    const float* Dparam    = (const float*)d_in[12];
    const float* outproj_w = (const float*)d_in[13];

    float* ws = (float*)d_ws;
    const size_t SZ_D  = (size_t)TOK*D;    // 1,048,576 floats
    const size_t SZ_DI = (size_t)TOK*DI;   // 2,097,152 floats
    float* h     = ws; ws += SZ_D;
    float* res0  = ws; ws += SZ_D;
    float* res1  = ws; ws += SZ_D;
    float* cur   = ws; ws += SZ_D;
    float* xm    = ws; ws += SZ_DI;
    float* z     = ws; ws += SZ_DI;
    float* Apub  = ws; ws += SZ_DI;   // NSTREAM*NC*NS*DI == SZ_DI
    float* Bpub  = ws; ws += SZ_DI;
    float* Ppub  = ws; ws += SZ_DI;
    ushort* wall = (ushort*)ws;                 // packed bf16 weights, 720896 ushorts
    ushort* wbd  = wall;                        // (128,256)       32768
    ushort* wbi  = wall + 32768;                // (6,512,128)    393216
    ushort* wbo  = wall + 425984;               // (6,128,256)    196608
    ushort* wbx  = wall + 622592;               // (6,64,256) pad  98304
    int* flags   = (int*)(wall + 720896);       // 3 layers x 512

    k_cvtall<<<2816, 256, 0, stream>>>(convd_w, in_proj_w, outproj_w, xproj_w, wall, flags);
    k_down<<<dim3(64, 2), 256, 0, stream>>>(x, wbd, convd_b, h);

    // res ping-pong: blk0 -> res0, blk1 -> res1, blk2 -> res0 (final reads res0)
    float* resin[3]  = { nullptr, res0, res1 };
    float* resout[3] = { res0,    res1, res0 };
    for (int blk = 0; blk < 3; ++blk){
        const float* ci = (blk==0) ? h : cur;
        const float* ri = (blk==0) ? h : resin[blk];
        k_fused_in<<<dim3(TOK/64, 8), 256, 0, stream>>>(ci, ri, resout[blk], ln_w, ln_b,
                                                        wbi, xm, z, blk, blk==0);
        k_mega<<<dim3(NC, NSTREAM), 256, 0, stream>>>(xm, z, conv_w, conv_b, wbx,
                                                      dtproj_w, dtproj_b, A_log, Dparam, wbo,
                                                      Apub, Bpub, Ppub, flags + blk*NSTREAM*NC,
                                                      cur, blk);
    }

    k_final<<<dim3(L, B), 128, 0, stream>>>(cur, res0, (float*)d_out);
}

// Round 8
// 740.780 us; speedup vs baseline: 1.6158x; 1.6158x over previous
//
#include <hip/hip_runtime.h>
#include <hip/hip_bf16.h>
#include <hip/hip_cooperative_groups.h>
#include <math.h>

namespace cg = cooperative_groups;

// Problem constants
#define B    2
#define CIN  64
#define LIN  8192
#define L    2048
#define D    128
#define DI   256
#define NS   16
#define RK   8
#define NSTREAM 4        // (dir, batch): s = dir*2 + b
#define CH   32          // coop chunk length (tokens per block)
#define NCH  (L/CH)      // 64 chunks per stream
#define NBLK 256         // coop grid: NSTREAM*NCH
#define TOK  (NSTREAM*L) // 8192
#define SZ_D ((size_t)TOK*D)    // 1,048,576 floats

typedef short  bfrag __attribute__((ext_vector_type(8)));
typedef float  facc  __attribute__((ext_vector_type(4)));
#define MFMA __builtin_amdgcn_mfma_f32_16x16x32_bf16

__device__ __forceinline__ float sigmoidf_(float x){ return 1.f/(1.f+__expf(-x)); }
__device__ __forceinline__ float siluf_(float x){ return x*sigmoidf_(x); }
__device__ __forceinline__ ushort f2bf(float f){
    unsigned u = __float_as_uint(f);
    u += 0x7fffu + ((u>>16)&1u);
    return (ushort)(u>>16);
}
__device__ __forceinline__ float bf2f(ushort u){ return __uint_as_float(((unsigned)u)<<16); }
__device__ __forceinline__ float softplusf_(float t){
    return (t > 20.f) ? t : __logf(1.f + __expf(t));
}

struct KP {
    const float *x, *convd_w, *convd_b, *ln_w, *ln_b, *in_proj_w, *conv_w, *conv_b,
                *xproj_w, *dtproj_w, *dtproj_b, *A_log, *Dparam, *outproj_w;
    float *h, *res, *cur, *Apub, *Bend, *out;
    ushort *wall, *bxm;
};

// ================= cooperative all-in-one kernel =================
__global__ void k_all(KP p){
    cg::grid_group grid = cg::this_grid();
    __shared__ ushort smA [CH*264];   // P1 patch / P2 LN-out (stride 136) / P3 sx
    __shared__ ushort smXm[CH*264];   // xm bf16; reused as g in P3c
    __shared__ ushort smZ [CH*264];   // z bf16
    __shared__ float  smDbc[CH*68];   // xproj out: 32 tok x 40(pad 68)
    const int tid = threadIdx.x;
    const int bi  = blockIdx.x;
    ushort* wbd = p.wall;             // (128,256)
    ushort* wbi = p.wall + 32768;     // (6,512,128)
    ushort* wbo = p.wall + 425984;    // (6,128,256)
    ushort* wbx = p.wall + 622592;    // (6,64,256) padded

    // ---- P0: weight cvt ----
    for (int i = bi*256 + tid; i < 720896; i += NBLK*256){
        ushort v;
        if (i < 32768)       v = f2bf(p.convd_w[i]);
        else if (i < 425984) v = f2bf(p.in_proj_w[i-32768]);
        else if (i < 622592) v = f2bf(p.outproj_w[i-425984]);
        else {
            int t = i - 622592;
            int k = t & 255, nr = (t>>8) & 63, j = t>>14;
            v = (nr < 40) ? f2bf(p.xproj_w[((size_t)j*40 + nr)*256 + k]) : (ushort)0;
        }
        p.wall[i] = v;
    }
    grid.sync();

    // ---- P1: downsample (block -> 16 tokens x 128 cols) ----
    {
        int m0 = bi*16;
        int b = m0 >> 11, l0 = m0 & 2047;
        for (int idx = tid; idx < 1024; idx += 256){
            int t = idx & 15, c = idx >> 4;
            float4 v = *(const float4*)(p.x + ((size_t)(b*CIN + c))*LIN + 4*(l0+t));
            ushort4 o; o.x=f2bf(v.x); o.y=f2bf(v.y); o.z=f2bf(v.z); o.w=f2bf(v.w);
            *(ushort4*)&smA[t*264 + c*4] = o;
        }
        __syncthreads();
        int w = tid>>6, lane = tid&63, q = lane>>4, r = lane&15;
        facc acc[2] = {};
        const ushort* bp0 = wbd + (size_t)(w*32 + r)*256 + q*8;
        const ushort* bp1 = bp0 + 16*256;
        #pragma unroll
        for (int kb=0; kb<8; ++kb){
            bfrag a  = *(bfrag*)&smA[r*264 + kb*32 + q*8];
            bfrag b0 = *(const bfrag*)(bp0 + kb*32);
            bfrag b1 = *(const bfrag*)(bp1 + kb*32);
            acc[0] = MFMA(a,b0,acc[0],0,0,0);
            acc[1] = MFMA(a,b1,acc[1],0,0,0);
        }
        #pragma unroll
        for (int ct=0; ct<2; ++ct){
            int col = w*32 + ct*16 + r;
            float bv = p.convd_b[col];
            #pragma unroll
            for (int r2=0; r2<4; ++r2){
                int row = m0 + q*4 + r2;
                int bb = row >> 11, l = row & 2047;
                float v = siluf_(acc[ct][r2] + bv);
                p.h[((size_t)(bb*L + l))*D + col] = v;
                p.h[((size_t)((2+bb)*L + (L-1-l)))*D + col] = v;
            }
        }
    }
    grid.sync();

    const int s = bi >> 6, c = bi & 63;
    const int base_tok = s*L + c*CH;

    for (int blk = 0; blk < 3; ++blk){
        const int j = (s>>1)*3 + blk;

        // ---- P2: residual + LN + in_proj (block owns its 32 tokens) ----
        {
            const float* curIn = (blk==0) ? p.h : p.cur;
            int t = tid >> 3, g8 = tid & 7;
            size_t off = (size_t)(base_tok + t)*D + g8*16;
            float4 v[4];
            const float4* cp = (const float4*)(curIn + off);
            #pragma unroll
            for (int i=0;i<4;++i) v[i] = cp[i];
            if (blk){
                const float4* rp = (const float4*)(p.res + off);
                #pragma unroll
                for (int i=0;i<4;++i){ float4 rv=rp[i]; v[i].x+=rv.x; v[i].y+=rv.y; v[i].z+=rv.z; v[i].w+=rv.w; }
            }
            {
                float4* ro = (float4*)(p.res + off);
                #pragma unroll
                for (int i=0;i<4;++i) ro[i] = v[i];
            }
            float s1=0.f, s2=0.f;
            #pragma unroll
            for (int i=0;i<4;++i){
                s1 += v[i].x+v[i].y+v[i].z+v[i].w;
                s2 += v[i].x*v[i].x+v[i].y*v[i].y+v[i].z*v[i].z+v[i].w*v[i].w;
            }
            s1 += __shfl_xor(s1,1); s2 += __shfl_xor(s2,1);
            s1 += __shfl_xor(s1,2); s2 += __shfl_xor(s2,2);
            s1 += __shfl_xor(s1,4); s2 += __shfl_xor(s2,4);
            float mean = s1*(1.f/128.f);
            float var  = s2*(1.f/128.f) - mean*mean;
            float rstd = rsqrtf(var + 1e-5f);
            const float4* lwp = (const float4*)(p.ln_w + j*D + g8*16);
            const float4* lbp = (const float4*)(p.ln_b + j*D + g8*16);
            #pragma unroll
            for (int i=0;i<4;++i){
                float4 lw = lwp[i], lb = lbp[i];
                ushort4 o;
                o.x = f2bf((v[i].x-mean)*rstd*lw.x + lb.x);
                o.y = f2bf((v[i].y-mean)*rstd*lw.y + lb.y);
                o.z = f2bf((v[i].z-mean)*rstd*lw.z + lb.z);
                o.w = f2bf((v[i].w-mean)*rstd*lw.w + lb.w);
                *(ushort4*)&smA[t*136 + g8*16 + i*4] = o;
            }
        }
        __syncthreads();
        // in_proj MFMA: M=32 (2 rt), N=512; wave w -> cols [w*128, w*128+128)
        {
            int w = tid>>6, lane = tid&63, q = lane>>4, r = lane&15;
            bfrag a[2][4];
            #pragma unroll
            for (int rt=0; rt<2; ++rt)
            #pragma unroll
            for (int kb=0; kb<4; ++kb)
                a[rt][kb] = *(bfrag*)&smA[(rt*16 + r)*136 + kb*32 + q*8];
            #pragma unroll
            for (int ct=0; ct<8; ++ct){
                int n0 = w*128 + ct*16;
                const ushort* bp = wbi + ((size_t)j*512 + n0 + r)*128 + q*8;
                facc a0 = {}, a1 = {};
                #pragma unroll
                for (int kb=0; kb<4; ++kb){
                    bfrag bv = *(const bfrag*)(bp + kb*32);
                    a0 = MFMA(a[0][kb], bv, a0, 0,0,0);
                    a1 = MFMA(a[1][kb], bv, a1, 0,0,0);
                }
                int colL = n0 + r;
                if (colL < DI){
                    #pragma unroll
                    for (int r2=0;r2<4;++r2){
                        smXm[(q*4+r2)*264 + colL]      = f2bf(a0[r2]);
                        smXm[(16+q*4+r2)*264 + colL]   = f2bf(a1[r2]);
                    }
                } else {
                    int cz = colL - DI;
                    #pragma unroll
                    for (int r2=0;r2<4;++r2){
                        smZ[(q*4+r2)*264 + cz]    = f2bf(a0[r2]);
                        smZ[(16+q*4+r2)*264 + cz] = f2bf(a1[r2]);
                    }
                }
            }
        }
        __syncthreads();
        // boundary halo for next chunk's conv: last 3 tokens of xm
        for (int idx = tid; idx < 768; idx += 256){
            int k3 = idx >> 8, dd = idx & 255;
            p.bxm[(size_t)bi*768 + idx] = smXm[(29+k3)*264 + dd];
        }
        grid.sync();

        // per-thread (d = tid) params
        float A[NS], wv[RK];
        {
            const float* ar = p.A_log + ((size_t)j*DI + tid)*NS;
            #pragma unroll
            for (int n=0;n<NS;++n) A[n] = -__expf(ar[n]);
            const float* wr = p.dtproj_w + ((size_t)j*DI + tid)*RK;
            #pragma unroll
            for (int r=0;r<RK;++r) wv[r] = wr[r];
        }
        float bb2 = p.dtproj_b[j*DI + tid];
        float Dpd = p.Dparam[j*DI + tid];

        // ---- P3a: conv+silu -> sx; xproj MFMA -> smDbc; local scan summary ----
        {
            const float* w4 = p.conv_w + ((size_t)j*DI + tid)*4;
            float cw0=w4[0], cw1=w4[1], cw2=w4[2], cw3=w4[3];
            float cbb = p.conv_b[j*DI + tid];
            float xm1=0.f, xm2=0.f, xm3=0.f;
            if (c > 0){
                const ushort* bp = p.bxm + (size_t)(bi-1)*768;
                xm3 = bf2f(bp[0*256 + tid]);
                xm2 = bf2f(bp[1*256 + tid]);
                xm1 = bf2f(bp[2*256 + tid]);
            }
            #pragma unroll 4
            for (int i=0;i<CH;++i){
                float x0 = bf2f(smXm[i*264 + tid]);
                float v = siluf_(cbb + cw3*x0 + cw2*xm1 + cw1*xm2 + cw0*xm3);
                smA[i*264 + tid] = f2bf(v);
                xm3 = xm2; xm2 = xm1; xm1 = x0;
            }
        }
        __syncthreads();
        {   // xproj MFMA: M=32, N=64; wave w -> cols [w*16, w*16+16)
            int w = tid>>6, lane = tid&63, q = lane>>4, r = lane&15;
            facc a0 = {}, a1 = {};
            const ushort* bp = wbx + ((size_t)j*64 + w*16 + r)*256 + q*8;
            #pragma unroll
            for (int kb=0; kb<8; ++kb){
                bfrag av0 = *(bfrag*)&smA[(r)*264 + kb*32 + q*8];
                bfrag av1 = *(bfrag*)&smA[(16+r)*264 + kb*32 + q*8];
                bfrag bv  = *(const bfrag*)(bp + kb*32);
                a0 = MFMA(av0, bv, a0, 0,0,0);
                a1 = MFMA(av1, bv, a1, 0,0,0);
            }
            int col = w*16 + r;
            #pragma unroll
            for (int r2=0;r2<4;++r2){
                smDbc[(q*4+r2)*68 + col]    = a0[r2];
                smDbc[(16+q*4+r2)*68 + col] = a1[r2];
            }
        }
        __syncthreads();
        {   // local scan summary
            float ap[NS], hs[NS];
            #pragma unroll
            for (int n=0;n<NS;++n){ ap[n]=1.f; hs[n]=0.f; }
            #pragma unroll 4
            for (int l=0;l<CH;++l){
                float t = bb2;
                #pragma unroll
                for (int r=0;r<RK;++r) t += smDbc[l*68+r]*wv[r];
                float dtv = softplusf_(t);
                float xv  = bf2f(smA[l*264 + tid]);
                float dbx = dtv*xv;
                #pragma unroll
                for (int n=0;n<NS;++n){
                    float dA = __expf(dtv*A[n]);
                    ap[n] *= dA;
                    hs[n] = dA*hs[n] + dbx*smDbc[l*68+8+n];
                }
            }
            size_t pb = (size_t)bi*4096 + tid;
            #pragma unroll
            for (int n=0;n<NS;++n){
                p.Apub[pb + (size_t)n*256] = ap[n];
                p.Bend[pb + (size_t)n*256] = hs[n];
            }
        }
        grid.sync();

        // ---- P3b: fold chunk summaries (16384 threads active) ----
        {
            int gt = bi*256 + tid;
            if (gt < 16384){
                int ss = gt >> 12, nd = gt & 4095;
                size_t base = (size_t)ss*NCH*4096 + nd;
                float hcar = 0.f;
                for (int c0=0; c0<NCH; c0+=16){
                    float a[16], b[16];
                    #pragma unroll
                    for (int i=0;i<16;++i){
                        a[i] = p.Apub[base + (size_t)(c0+i)*4096];
                        b[i] = p.Bend[base + (size_t)(c0+i)*4096];
                    }
                    #pragma unroll
                    for (int i=0;i<16;++i){
                        p.Bend[base + (size_t)(c0+i)*4096] = hcar;  // carry INTO chunk
                        hcar = a[i]*hcar + b[i];
                    }
                }
            }
        }
        grid.sync();

        // ---- P3c: apply scan with carry + gate -> g (smXm), out_proj -> cur ----
        {
            float hs[NS];
            size_t pb = (size_t)bi*4096 + tid;
            #pragma unroll
            for (int n=0;n<NS;++n) hs[n] = p.Bend[pb + (size_t)n*256];
            #pragma unroll 4
            for (int l=0;l<CH;++l){
                float t = bb2;
                #pragma unroll
                for (int r=0;r<RK;++r) t += smDbc[l*68+r]*wv[r];
                float dtv = softplusf_(t);
                float xv  = bf2f(smA[l*264 + tid]);
                float dbx = dtv*xv;
                float pacc = 0.f;
                #pragma unroll
                for (int n=0;n<NS;++n){
                    float dA = __expf(dtv*A[n]);
                    hs[n] = dA*hs[n] + dbx*smDbc[l*68+8+n];
                    pacc += hs[n]*smDbc[l*68+24+n];
                }
                float zv = bf2f(smZ[l*264 + tid]);
                smXm[l*264 + tid] = f2bf((pacc + Dpd*xv)*siluf_(zv));
            }
            __syncthreads();
            // out_proj: M=32 (2 rt), N=128; wave w -> cols [w*32, w*32+32)
            int w = tid>>6, lane = tid&63, q = lane>>4, r = lane&15;
            facc acc[2][2] = {};
            const ushort* b0p = wbo + ((size_t)j*128 + w*32 + r)*256 + q*8;
            const ushort* b1p = b0p + 16*256;
            #pragma unroll
            for (int kb=0; kb<8; ++kb){
                bfrag av0 = *(bfrag*)&smXm[(r)*264 + kb*32 + q*8];
                bfrag av1 = *(bfrag*)&smXm[(16+r)*264 + kb*32 + q*8];
                bfrag bv0 = *(const bfrag*)(b0p + kb*32);
                bfrag bv1 = *(const bfrag*)(b1p + kb*32);
                acc[0][0] = MFMA(av0,bv0,acc[0][0],0,0,0);
                acc[0][1] = MFMA(av0,bv1,acc[0][1],0,0,0);
                acc[1][0] = MFMA(av1,bv0,acc[1][0],0,0,0);
                acc[1][1] = MFMA(av1,bv1,acc[1][1],0,0,0);
            }
            #pragma unroll
            for (int rt=0; rt<2; ++rt)
            #pragma unroll
            for (int ctt=0; ctt<2; ++ctt){
                int col = w*32 + ctt*16 + r;
                #pragma unroll
                for (int r2=0;r2<4;++r2){
                    int row = base_tok + rt*16 + q*4 + r2;
                    p.cur[(size_t)row*D + col] = acc[rt][ctt][r2];
                }
            }
        }
        grid.sync();
    }

    // ---- P4: final combine ----
    for (int idx = bi*256 + tid; idx < 2*L*D; idx += NBLK*256){
        int d = idx & 127, l = (idx>>7) & 2047, b = idx>>18;
        size_t tf  = ((size_t)(b*L + l))*D + d;
        size_t tbk = ((size_t)((2+b)*L + (L-1-l)))*D + d;
        float f  = p.cur[tf] + p.res[tf];
        float bw = p.cur[tbk] + p.res[tbk];
        p.out[((size_t)(b*D + d))*L + l] = f + bw;
        p.out[(size_t)2*D*L + tf] = p.res[tf];
        size_t tb2 = ((size_t)((2+b)*L + l))*D + d;
        p.out[(size_t)2*D*L + tb2] = p.res[tb2];
    }
}

// ================= fallback path (R6 structure, verified) =================
#define CHUNKF 16
#define NCF   (L/CHUNKF)

__global__ void k_cvtall2(const float* __restrict__ cw, const float* __restrict__ ipw,
                          const float* __restrict__ opw, const float* __restrict__ xpw,
                          ushort* __restrict__ dst){
    int i = blockIdx.x*256 + threadIdx.x;
    ushort v;
    if (i < 32768)       v = f2bf(cw[i]);
    else if (i < 425984) v = f2bf(ipw[i-32768]);
    else if (i < 622592) v = f2bf(opw[i-425984]);
    else {
        int t = i - 622592;
        int k = t & 255, nr = (t>>8) & 63, j = t>>14;
        v = (nr < 40) ? f2bf(xpw[((size_t)j*40 + nr)*256 + k]) : (ushort)0;
    }
    dst[i] = v;
}

__global__ void k_down(const float* __restrict__ x, const ushort* __restrict__ wd,
                       const float* __restrict__ bias, float* __restrict__ h){
    __shared__ ushort sxd[64*264];
    int tid = threadIdx.x;
    int m0 = blockIdx.x*64;
    int b = m0 >> 11;
    int l0 = m0 & 2047;
    for (int idx = tid; idx < 64*64; idx += 256){
        int t = idx & 63, cc = idx >> 6;
        float4 v = *(const float4*)(x + ((size_t)(b*CIN + cc))*LIN + 4*(l0+t));
        ushort4 o; o.x=f2bf(v.x); o.y=f2bf(v.y); o.z=f2bf(v.z); o.w=f2bf(v.w);
        *(ushort4*)&sxd[t*264 + cc*4] = o;
    }
    __syncthreads();
    int w = tid>>6, lane = tid&63, rw = w>>1, cw = w&1;
    int q = lane>>4, r = lane&15;
    int n0 = blockIdx.y*64 + cw*32;
    const ushort* b0p = wd + (size_t)(n0 + r)*256 + q*8;
    const ushort* b1p = b0p + (size_t)16*256;
    facc acc[2][2] = {};
    #pragma unroll
    for (int kb=0; kb<8; ++kb){
        bfrag a0 = *(bfrag*)&sxd[(rw*32 + r)*264 + kb*32 + q*8];
        bfrag a1 = *(bfrag*)&sxd[(rw*32 + 16 + r)*264 + kb*32 + q*8];
        bfrag b0 = *(const bfrag*)(b0p + kb*32);
        bfrag b1 = *(const bfrag*)(b1p + kb*32);
        acc[0][0] = MFMA(a0,b0,acc[0][0],0,0,0);
        acc[0][1] = MFMA(a0,b1,acc[0][1],0,0,0);
        acc[1][0] = MFMA(a1,b0,acc[1][0],0,0,0);
        acc[1][1] = MFMA(a1,b1,acc[1][1],0,0,0);
    }
    #pragma unroll
    for (int im=0; im<2; ++im)
    #pragma unroll
    for (int in=0; in<2; ++in){
        int col = n0 + in*16 + r;
        float bv = bias[col];
        #pragma unroll
        for (int r2=0; r2<4; ++r2){
            int row = m0 + rw*32 + im*16 + q*4 + r2;
            int bb = row >> 11, l = row & 2047;
            float v = siluf_(acc[im][in][r2] + bv);
            h[((size_t)(bb*L + l))*D + col] = v;
            h[((size_t)((2+bb)*L + (L-1-l)))*D + col] = v;
        }
    }
}

__global__ void k_fused_in(const float* __restrict__ curIn, const float* __restrict__ resIn,
                           float* __restrict__ resOut,
                           const float* __restrict__ lnw, const float* __restrict__ lnb,
                           const ushort* __restrict__ wbi,
                           float* __restrict__ xm, float* __restrict__ z, int blk, int first){
    __shared__ ushort sh[64*136];
    int m0 = blockIdx.x*64;
    int s = m0 >> 11; int j = (s>>1)*3 + blk;
    int tid = threadIdx.x;
    int t = tid >> 2, sub = tid & 3;
    size_t rowoff = (size_t)(m0 + t)*D + sub*32;
    float4 v[8];
    const float4* cp = (const float4*)(curIn + rowoff);
    #pragma unroll
    for (int i=0;i<8;++i) v[i] = cp[i];
    if (!first){
        const float4* rp = (const float4*)(resIn + rowoff);
        #pragma unroll
        for (int i=0;i<8;++i){ float4 rv = rp[i]; v[i].x+=rv.x; v[i].y+=rv.y; v[i].z+=rv.z; v[i].w+=rv.w; }
    }
    if (blockIdx.y == 0){
        float4* ro = (float4*)(resOut + rowoff);
        #pragma unroll
        for (int i=0;i<8;++i) ro[i] = v[i];
    }
    float s1 = 0.f, s2 = 0.f;
    #pragma unroll
    for (int i=0;i<8;++i){
        s1 += v[i].x + v[i].y + v[i].z + v[i].w;
        s2 += v[i].x*v[i].x + v[i].y*v[i].y + v[i].z*v[i].z + v[i].w*v[i].w;
    }
    s1 += __shfl_xor(s1, 1); s2 += __shfl_xor(s2, 1);
    s1 += __shfl_xor(s1, 2); s2 += __shfl_xor(s2, 2);
    float mean = s1*(1.f/128.f);
    float var  = s2*(1.f/128.f) - mean*mean;
    float rstd = rsqrtf(var + 1e-5f);
    const float4* lwp = (const float4*)(lnw + j*D + sub*32);
    const float4* lbp = (const float4*)(lnb + j*D + sub*32);
    #pragma unroll
    for (int i=0;i<8;++i){
        float4 lw = lwp[i], lb = lbp[i];
        ushort4 o;
        o.x = f2bf((v[i].x-mean)*rstd*lw.x + lb.x);
        o.y = f2bf((v[i].y-mean)*rstd*lw.y + lb.y);
        o.z = f2bf((v[i].z-mean)*rstd*lw.z + lb.z);
        o.w = f2bf((v[i].w-mean)*rstd*lw.w + lb.w);
        *(ushort4*)&sh[t*136 + sub*32 + i*4] = o;
    }
    __syncthreads();
    int w = tid>>6, lane = tid&63, rw = w>>1, cw = w&1;
    int q = lane>>4, r = lane&15;
    int n0 = blockIdx.y*64 + cw*32;
    const ushort* b0p = wbi + ((size_t)j*512 + n0 + r)*128 + q*8;
    const ushort* b1p = b0p + (size_t)16*128;
    facc acc[2][2] = {};
    #pragma unroll
    for (int kb=0; kb<4; ++kb){
        bfrag a0 = *(bfrag*)&sh[(rw*32 + r)*136 + kb*32 + q*8];
        bfrag a1 = *(bfrag*)&sh[(rw*32 + 16 + r)*136 + kb*32 + q*8];
        bfrag b0 = *(const bfrag*)(b0p + kb*32);
        bfrag b1 = *(const bfrag*)(b1p + kb*32);
        acc[0][0] = MFMA(a0,b0,acc[0][0],0,0,0);
        acc[0][1] = MFMA(a0,b1,acc[0][1],0,0,0);
        acc[1][0] = MFMA(a1,b0,acc[1][0],0,0,0);
        acc[1][1] = MFMA(a1,b1,acc[1][1],0,0,0);
    }
    #pragma unroll
    for (int im=0; im<2; ++im)
    #pragma unroll
    for (int in=0; in<2; ++in){
        int e = n0 + in*16 + r;
        #pragma unroll
        for (int r2=0; r2<4; ++r2){
            int row = m0 + rw*32 + im*16 + q*4 + r2;
            float vv = acc[im][in][r2];
            if (e < DI) xm[(size_t)row*DI + e] = vv;
            else        z [(size_t)row*DI + (e-DI)] = vv;
        }
    }
}

__global__ void k_convx(const float* __restrict__ xm, const float* __restrict__ cw,
                        const float* __restrict__ cb, const ushort* __restrict__ wbx,
                        float* __restrict__ xc, float* __restrict__ dtr,
                        float* __restrict__ Bc, float* __restrict__ Cc, int blk){
    __shared__ ushort sx[32*264];
    int m0 = blockIdx.x*32;
    int s = m0 >> 11; int j = (s>>1)*3 + blk;
    int sl0 = m0 & 2047;
    int d = threadIdx.x;
    const float* w4 = cw + ((size_t)j*DI + d)*4;
    float w0=w4[0], w1=w4[1], w2=w4[2], w3=w4[3];
    float bb = cb[j*DI + d];
    float xm1=0.f, xm2=0.f, xm3=0.f;
    if (sl0 > 0){
        xm1 = xm[(size_t)(m0-1)*DI + d];
        xm2 = xm[(size_t)(m0-2)*DI + d];
        xm3 = xm[(size_t)(m0-3)*DI + d];
    }
    #pragma unroll 4
    for (int i=0;i<32;++i){
        float x0 = xm[(size_t)(m0+i)*DI + d];
        float acc = bb + w3*x0 + w2*xm1 + w1*xm2 + w0*xm3;
        float v = siluf_(acc);
        xc[(size_t)(m0+i)*DI + d] = v;
        sx[i*264 + d] = f2bf(v);
        xm3 = xm2; xm2 = xm1; xm1 = x0;
    }
    __syncthreads();
    int wv = d>>6, lane = d&63, q = lane>>4, r = lane&15;
    int n0 = wv*16;
    facc acc2[2] = {};
    const ushort* bp = wbx + ((size_t)j*64 + n0 + r)*256 + q*8;
    #pragma unroll
    for (int kb=0; kb<8; ++kb){
        bfrag a0 = *(bfrag*)&sx[r*264 + kb*32 + q*8];
        bfrag a1 = *(bfrag*)&sx[(r+16)*264 + kb*32 + q*8];
        bfrag b  = *(const bfrag*)(bp + kb*32);
        acc2[0] = MFMA(a0,b,acc2[0],0,0,0);
        acc2[1] = MFMA(a1,b,acc2[1],0,0,0);
    }
    int col = n0 + r;
    #pragma unroll
    for (int im=0; im<2; ++im){
        #pragma unroll
        for (int r2=0; r2<4; ++r2){
            int row = m0 + im*16 + q*4 + r2;
            float vv = acc2[im][r2];
            if      (col < 8)  dtr[(size_t)row*RK + col] = vv;
            else if (col < 24) Bc [(size_t)row*NS + (col-8)] = vv;
            else if (col < 40) Cc [(size_t)row*NS + (col-24)] = vv;
        }
    }
}

__global__ void k_scan1(const float* __restrict__ dtr, const float* __restrict__ xcv,
                        const float* __restrict__ Bc, const float* __restrict__ A_log,
                        const float* __restrict__ Wdt, const float* __restrict__ bdt,
                        float* __restrict__ Aprod, float* __restrict__ Bend, int blk){
    int c = blockIdx.x, s = blockIdx.y; int j = (s>>1)*3 + blk;
    int d = threadIdx.x;
    __shared__ float sB[CHUNKF*NS];
    __shared__ float sdtr[CHUNKF*RK];
    int base_tok = s*L + c*CHUNKF;
    sB[d] = Bc[(size_t)base_tok*NS + d];
    if (d < CHUNKF*RK) sdtr[d] = dtr[(size_t)base_tok*RK + d];
    float A[NS];
    const float* ar = A_log + ((size_t)j*DI + d)*NS;
    #pragma unroll
    for (int n=0;n<NS;++n) A[n] = -__expf(ar[n]);
    float wv[RK];
    const float* wr = Wdt + ((size_t)j*DI + d)*RK;
    #pragma unroll
    for (int r=0;r<RK;++r) wv[r] = wr[r];
    float bb = bdt[j*DI + d];
    float ap[NS], hs[NS];
    #pragma unroll
    for (int n=0;n<NS;++n){ ap[n]=1.f; hs[n]=0.f; }
    __syncthreads();
    #pragma unroll 4
    for (int l=0;l<CHUNKF;++l){
        float t = bb;
        #pragma unroll
        for (int r=0;r<RK;++r) t += sdtr[l*RK+r]*wv[r];
        float dtv = softplusf_(t);
        float xv  = xcv[(size_t)(base_tok+l)*DI + d];
        float dbx = dtv*xv;
        #pragma unroll
        for (int n=0;n<NS;++n){
            float dA = __expf(dtv*A[n]);
            ap[n] *= dA;
            hs[n] = dA*hs[n] + dbx*sB[l*NS+n];
        }
    }
    size_t obase = ((size_t)(s*NCF + c)*NS)*DI + d;
    #pragma unroll
    for (int n=0;n<NS;++n){
        Aprod[obase + (size_t)n*DI] = ap[n];
        Bend [obase + (size_t)n*DI] = hs[n];
    }
}

__global__ void k_scanmid(const float* __restrict__ Aprod, float* __restrict__ Bend){
    int tid = blockIdx.x*128 + threadIdx.x;
    int s = tid >> 12;
    int nd = tid & 4095;
    const size_t stride = (size_t)NS*DI;
    size_t base = ((size_t)s*NCF)*stride + nd;
    float h = 0.f;
    for (int c0=0; c0<NCF; c0+=16){
        float a[16], b[16];
        #pragma unroll
        for (int i=0;i<16;++i){
            a[i] = Aprod[base + (size_t)(c0+i)*stride];
            b[i] = Bend [base + (size_t)(c0+i)*stride];
        }
        #pragma unroll
        for (int i=0;i<16;++i){
            Bend[base + (size_t)(c0+i)*stride] = h;
            h = a[i]*h + b[i];
        }
    }
}

__global__ void k_scan2out(const float* __restrict__ dtr, const float* __restrict__ xcv,
                           const float* __restrict__ Bc, const float* __restrict__ Cc,
                           const float* __restrict__ A_log,
                           const float* __restrict__ Wdt, const float* __restrict__ bdt,
                           const float* __restrict__ h0, const float* __restrict__ z,
                           const float* __restrict__ Dp, const ushort* __restrict__ wbo,
                           float* __restrict__ cur, int blk){
    int c = blockIdx.x, s = blockIdx.y; int j = (s>>1)*3 + blk;
    int d = threadIdx.x;
    __shared__ float sB[CHUNKF*NS], sC[CHUNKF*NS], sdtr[CHUNKF*RK];
    __shared__ ushort sg[CHUNKF*264];
    int base_tok = s*L + c*CHUNKF;
    sB[d] = Bc[(size_t)base_tok*NS + d];
    sC[d] = Cc[(size_t)base_tok*NS + d];
    if (d < CHUNKF*RK) sdtr[d] = dtr[(size_t)base_tok*RK + d];
    float A[NS];
    const float* ar = A_log + ((size_t)j*DI + d)*NS;
    #pragma unroll
    for (int n=0;n<NS;++n) A[n] = -__expf(ar[n]);
    float wv[RK];
    const float* wr = Wdt + ((size_t)j*DI + d)*RK;
    #pragma unroll
    for (int r=0;r<RK;++r) wv[r] = wr[r];
    float bb = bdt[j*DI + d];
    float Dpd = Dp[j*DI + d];
    float hs[NS];
    size_t ibase = ((size_t)(s*NCF + c)*NS)*DI + d;
    #pragma unroll
    for (int n=0;n<NS;++n) hs[n] = h0[ibase + (size_t)n*DI];
    __syncthreads();
    #pragma unroll 4
    for (int l=0;l<CHUNKF;++l){
        float t = bb;
        #pragma unroll
        for (int r=0;r<RK;++r) t += sdtr[l*RK+r]*wv[r];
        float dtv = softplusf_(t);
        float xv  = xcv[(size_t)(base_tok+l)*DI + d];
        float dbx = dtv*xv;
        float p = 0.f;
        #pragma unroll
        for (int n=0;n<NS;++n){
            float dA = __expf(dtv*A[n]);
            hs[n] = dA*hs[n] + dbx*sB[l*NS+n];
            p += hs[n]*sC[l*NS+n];
        }
        float zv = z[(size_t)(base_tok+l)*DI + d];
        sg[l*264 + d] = f2bf((p + Dpd*xv)*siluf_(zv));
    }
    __syncthreads();
    int wvi = d>>6, lane = d&63, q = lane>>4, r = lane&15;
    int n0 = wvi*32;
    facc acc[2] = {};
    const ushort* b0p = wbo + ((size_t)j*128 + n0 + r)*256 + q*8;
    const ushort* b1p = b0p + (size_t)16*256;
    #pragma unroll
    for (int kb=0; kb<8; ++kb){
        bfrag a  = *(bfrag*)&sg[r*264 + kb*32 + q*8];
        bfrag b0 = *(const bfrag*)(b0p + kb*32);
        bfrag b1 = *(const bfrag*)(b1p + kb*32);
        acc[0] = MFMA(a,b0,acc[0],0,0,0);
        acc[1] = MFMA(a,b1,acc[1],0,0,0);
    }
    #pragma unroll
    for (int in=0; in<2; ++in){
        int col = n0 + in*16 + r;
        #pragma unroll
        for (int r2=0; r2<4; ++r2){
            int row = q*4 + r2;
            cur[(size_t)(base_tok+row)*D + col] = acc[in][r2];
        }
    }
}

__global__ void k_final(const float* __restrict__ cur, const float* __restrict__ res,
                        float* __restrict__ out){
    int l = blockIdx.x, b = blockIdx.y, d = threadIdx.x;
    int tf = (b*L + l)*D + d;
    int tbk = ((2+b)*L + (L-1-l))*D + d;
    float f  = cur[tf] + res[tf];
    float bw = cur[tbk] + res[tbk];
    out[((size_t)(b*D + d))*L + l] = f + bw;
    out[(size_t)2*D*L + (size_t)(b*L + l)*D + d] = res[tf];
    out[(size_t)2*D*L + (size_t)((2+b)*L + l)*D + d] = res[((2+b)*L + l)*D + d];
}

// ================= launch =================
extern "C" void kernel_launch(void* const* d_in, const int* in_sizes, int n_in,
                              void* d_out, int out_size, void* d_ws, size_t ws_size,
                              hipStream_t stream){
    KP p;
    p.x         = (const float*)d_in[0];
    p.convd_w   = (const float*)d_in[1];
    p.convd_b   = (const float*)d_in[2];
    p.ln_w      = (const float*)d_in[3];
    p.ln_b      = (const float*)d_in[4];
    p.in_proj_w = (const float*)d_in[5];
    p.conv_w    = (const float*)d_in[6];
    p.conv_b    = (const float*)d_in[7];
    p.xproj_w   = (const float*)d_in[8];
    p.dtproj_w  = (const float*)d_in[9];
    p.dtproj_b  = (const float*)d_in[10];
    p.A_log     = (const float*)d_in[11];
    p.Dparam    = (const float*)d_in[12];
    p.outproj_w = (const float*)d_in[13];
    p.out       = (float*)d_out;

    float* ws = (float*)d_ws;
    p.h    = ws; ws += SZ_D;
    p.res  = ws; ws += SZ_D;
    p.cur  = ws; ws += SZ_D;
    p.Apub = ws; ws += SZ_D;
    p.Bend = ws; ws += SZ_D;
    p.bxm  = (ushort*)ws;
    p.wall = p.bxm + (size_t)NBLK*768;
    float* ws2 = ws + 300000;   // past bxm(196608 us) + wall(720896 us) = 458752 floats

    void* args[] = { &p };
    hipError_t e = hipLaunchCooperativeKernel((const void*)k_all, dim3(NBLK), dim3(256),
                                              args, 0, stream);
    if (e == hipSuccess) return;

    // ---------- fallback: verified R6 multi-kernel path ----------
    (void)hipGetLastError();
    const size_t SZ_DI2 = (size_t)TOK*DI;
    float* ws3   = ws2 + 200000;      // safety gap
    float* res0  = p.res;             // reuse
    float* res1  = ws3; ws3 += SZ_D;
    float* xm    = ws3; ws3 += SZ_DI2;
    float* z     = ws3; ws3 += SZ_DI2;
    float* xc    = ws3; ws3 += SZ_DI2;
    float* Aprod = ws3; ws3 += SZ_DI2;
    float* Bend2 = ws3; ws3 += SZ_DI2;
    float* dtr   = ws3; ws3 += (size_t)TOK*RK;
    float* Bc    = ws3; ws3 += (size_t)TOK*NS;
    float* Cc    = ws3; ws3 += (size_t)TOK*NS;
    ushort* wall = p.wall;
    ushort* wbd  = wall;
    ushort* wbi  = wall + 32768;
    ushort* wbo  = wall + 425984;
    ushort* wbx  = wall + 622592;

    k_cvtall2<<<2816, 256, 0, stream>>>(p.convd_w, p.in_proj_w, p.outproj_w, p.xproj_w, wall);
    k_down<<<dim3(64, 2), 256, 0, stream>>>(p.x, wbd, p.convd_b, p.h);

    float* resin[3]  = { nullptr, res0, res1 };
    float* resout[3] = { res0,    res1, res0 };
    for (int blk = 0; blk < 3; ++blk){
        const float* ci = (blk==0) ? p.h : p.cur;
        const float* ri = (blk==0) ? p.h : resin[blk];
        k_fused_in<<<dim3(TOK/64, 8), 256, 0, stream>>>(ci, ri, resout[blk], p.ln_w, p.ln_b,
                                                        wbi, xm, z, blk, blk==0);
        k_convx<<<TOK/32, 256, 0, stream>>>(xm, p.conv_w, p.conv_b, wbx, xc, dtr, Bc, Cc, blk);
        k_scan1<<<dim3(NCF, NSTREAM), 256, 0, stream>>>(dtr, xc, Bc, p.A_log, p.dtproj_w,
                                                        p.dtproj_b, Aprod, Bend2, blk);
        k_scanmid<<<128, 128, 0, stream>>>(Aprod, Bend2);
        k_scan2out<<<dim3(NCF, NSTREAM), 256, 0, stream>>>(dtr, xc, Bc, Cc, p.A_log,
                                                           p.dtproj_w, p.dtproj_b,
                                                           Bend2, z, p.Dparam, wbo, p.cur, blk);
    }
    k_final<<<dim3(L, B), 128, 0, stream>>>(p.cur, res0, p.out);
}

// Round 9
// 254.389 us; speedup vs baseline: 4.7053x; 2.9120x over previous
//
#include <hip/hip_runtime.h>
#include <hip/hip_bf16.h>
#include <math.h>

// Problem constants
#define B    2
#define CIN  64
#define LIN  8192
#define L    2048
#define D    128
#define DI   256
#define NS   16
#define RK   8
#define NSTREAM 4        // (dir, batch): s = dir*2 + b
#define CH   32          // tokens per chunk/block
#define NCH  (L/CH)      // 64 chunks per stream
#define TOK  (NSTREAM*L) // 8192
#define SZ_D ((size_t)TOK*D)     // 1,048,576 floats
#define SZ_DI ((size_t)TOK*DI)   // 2,097,152 floats
// LDS row strides (ushorts): start-bank pattern (12r+4q)%32 -> conflict-free b128
#define SXM 280
#define SHN 152

typedef short  bfrag __attribute__((ext_vector_type(8)));
typedef float  facc  __attribute__((ext_vector_type(4)));
#define MFMA __builtin_amdgcn_mfma_f32_16x16x32_bf16

__device__ __forceinline__ float sigmoidf_(float x){ return 1.f/(1.f+__expf(-x)); }
__device__ __forceinline__ float siluf_(float x){ return x*sigmoidf_(x); }
__device__ __forceinline__ ushort f2bf(float f){
    unsigned u = __float_as_uint(f);
    u += 0x7fffu + ((u>>16)&1u);
    return (ushort)(u>>16);
}
__device__ __forceinline__ float bf2f(ushort u){ return __uint_as_float(((unsigned)u)<<16); }
__device__ __forceinline__ float softplusf_(float t){
    return (t > 20.f) ? t : __logf(1.f + __expf(t));
}

// ---------------- weight conversion
// dst: wbd(32768) | wbi(393216) | wbo(196608) | wbx(98304, 40->64 pad)
__global__ void k_cvtall(const float* __restrict__ cw, const float* __restrict__ ipw,
                         const float* __restrict__ opw, const float* __restrict__ xpw,
                         ushort* __restrict__ dst){
    int i = blockIdx.x*256 + threadIdx.x;
    ushort v;
    if (i < 32768)       v = f2bf(cw[i]);
    else if (i < 425984) v = f2bf(ipw[i-32768]);
    else if (i < 622592) v = f2bf(opw[i-425984]);
    else {
        int t = i - 622592;
        int k = t & 255, nr = (t>>8) & 63, j = t>>14;
        v = (nr < 40) ? f2bf(xpw[((size_t)j*40 + nr)*256 + k]) : (ushort)0;
    }
    dst[i] = v;
}

// ---------------- fused patch-pack + downsample GEMM + bias + silu, dual write
__global__ void k_down(const float* __restrict__ x, const ushort* __restrict__ wd,
                       const float* __restrict__ bias, float* __restrict__ h){
    __shared__ ushort sxd[64*SXM];
    int tid = threadIdx.x;
    int m0 = blockIdx.x*64;
    int b = m0 >> 11;
    int l0 = m0 & 2047;
    for (int idx = tid; idx < 64*64; idx += 256){
        int t = idx & 63, cc = idx >> 6;
        float4 v = *(const float4*)(x + ((size_t)(b*CIN + cc))*LIN + 4*(l0+t));
        ushort4 o; o.x=f2bf(v.x); o.y=f2bf(v.y); o.z=f2bf(v.z); o.w=f2bf(v.w);
        *(ushort4*)&sxd[t*SXM + cc*4] = o;
    }
    __syncthreads();
    int w = tid>>6, lane = tid&63, rw = w>>1, cw = w&1;
    int q = lane>>4, r = lane&15;
    int n0 = blockIdx.y*64 + cw*32;
    const ushort* b0p = wd + (size_t)(n0 + r)*256 + q*8;
    const ushort* b1p = b0p + (size_t)16*256;
    facc acc[2][2] = {};
    #pragma unroll
    for (int kb=0; kb<8; ++kb){
        bfrag a0 = *(bfrag*)&sxd[(rw*32 + r)*SXM + kb*32 + q*8];
        bfrag a1 = *(bfrag*)&sxd[(rw*32 + 16 + r)*SXM + kb*32 + q*8];
        bfrag b0 = *(const bfrag*)(b0p + kb*32);
        bfrag b1 = *(const bfrag*)(b1p + kb*32);
        acc[0][0] = MFMA(a0,b0,acc[0][0],0,0,0);
        acc[0][1] = MFMA(a0,b1,acc[0][1],0,0,0);
        acc[1][0] = MFMA(a1,b0,acc[1][0],0,0,0);
        acc[1][1] = MFMA(a1,b1,acc[1][1],0,0,0);
    }
    #pragma unroll
    for (int im=0; im<2; ++im)
    #pragma unroll
    for (int in=0; in<2; ++in){
        int col = n0 + in*16 + r;
        float bv = bias[col];
        #pragma unroll
        for (int r2=0; r2<4; ++r2){
            int row = m0 + rw*32 + im*16 + q*4 + r2;
            int bb = row >> 11, l = row & 2047;
            float v = siluf_(acc[im][in][r2] + bv);
            h[((size_t)(bb*L + l))*D + col] = v;
            h[((size_t)((2+bb)*L + (L-1-l)))*D + col] = v;
        }
    }
}

// ---------------- k_head: resln + in_proj + conv + x_proj + scan1, per 32-token chunk
// grid 256 (bi = s*NCH + c), block 256
__global__ void __launch_bounds__(256,1)
k_head(const float* __restrict__ curIn, const float* __restrict__ resIn,
       float* __restrict__ resOut,
       const float* __restrict__ lnw, const float* __restrict__ lnb,
       const ushort* __restrict__ wbi, const ushort* __restrict__ wbx,
       const float* __restrict__ cw, const float* __restrict__ cb,
       const float* __restrict__ Wdt, const float* __restrict__ bdt,
       const float* __restrict__ A_log,
       float* __restrict__ z, float* __restrict__ xc,
       float* __restrict__ dtr, float* __restrict__ Bc, float* __restrict__ Cc,
       float* __restrict__ Aprod, float* __restrict__ Bend, int blk, int first){
    __shared__ ushort smHn[35*SHN];   // LN out: rows 0..31 owned, 32..34 halo
    __shared__ ushort smXm[35*SXM];   // xm bf16 (rows 32..34 = halo)
    __shared__ ushort smXc[32*SXM];   // conv out bf16
    __shared__ float  smDbc[32*68];   // xproj out
    const int tid = threadIdx.x;
    const int bi = blockIdx.x;
    const int s = bi >> 6, c = bi & 63;
    const int j = (s>>1)*3 + blk;
    const int base_tok = s*L + c*CH;

    // ---- residual + LN (owned 32 tokens; 8 lanes per token) ----
    {
        int t = tid >> 3, g8 = tid & 7;
        size_t off = (size_t)(base_tok + t)*D + g8*16;
        float4 v[4];
        const float4* cp = (const float4*)(curIn + off);
        #pragma unroll
        for (int i=0;i<4;++i) v[i] = cp[i];
        if (!first){
            const float4* rp = (const float4*)(resIn + off);
            #pragma unroll
            for (int i=0;i<4;++i){ float4 rv=rp[i]; v[i].x+=rv.x; v[i].y+=rv.y; v[i].z+=rv.z; v[i].w+=rv.w; }
        }
        {
            float4* ro = (float4*)(resOut + off);
            #pragma unroll
            for (int i=0;i<4;++i) ro[i] = v[i];
        }
        float s1=0.f, s2=0.f;
        #pragma unroll
        for (int i=0;i<4;++i){
            s1 += v[i].x+v[i].y+v[i].z+v[i].w;
            s2 += v[i].x*v[i].x+v[i].y*v[i].y+v[i].z*v[i].z+v[i].w*v[i].w;
        }
        s1 += __shfl_xor(s1,1); s2 += __shfl_xor(s2,1);
        s1 += __shfl_xor(s1,2); s2 += __shfl_xor(s2,2);
        s1 += __shfl_xor(s1,4); s2 += __shfl_xor(s2,4);
        float mean = s1*(1.f/128.f);
        float var  = s2*(1.f/128.f) - mean*mean;
        float rstd = rsqrtf(var + 1e-5f);
        const float4* lwp = (const float4*)(lnw + j*D + g8*16);
        const float4* lbp = (const float4*)(lnb + j*D + g8*16);
        #pragma unroll
        for (int i=0;i<4;++i){
            float4 lw = lwp[i], lb = lbp[i];
            ushort4 o;
            o.x = f2bf((v[i].x-mean)*rstd*lw.x + lb.x);
            o.y = f2bf((v[i].y-mean)*rstd*lw.y + lb.y);
            o.z = f2bf((v[i].z-mean)*rstd*lw.z + lb.z);
            o.w = f2bf((v[i].w-mean)*rstd*lw.w + lb.w);
            *(ushort4*)&smHn[t*SHN + g8*16 + i*4] = o;
        }
    }
    // ---- halo LN (3 tokens, threads 0..23; no res write) ----
    if (c > 0 && tid < 24){
        int t = tid >> 3, g8 = tid & 7;
        size_t off = (size_t)(base_tok - 3 + t)*D + g8*16;
        float4 v[4];
        const float4* cp = (const float4*)(curIn + off);
        #pragma unroll
        for (int i=0;i<4;++i) v[i] = cp[i];
        if (!first){
            const float4* rp = (const float4*)(resIn + off);
            #pragma unroll
            for (int i=0;i<4;++i){ float4 rv=rp[i]; v[i].x+=rv.x; v[i].y+=rv.y; v[i].z+=rv.z; v[i].w+=rv.w; }
        }
        float s1=0.f, s2=0.f;
        #pragma unroll
        for (int i=0;i<4;++i){
            s1 += v[i].x+v[i].y+v[i].z+v[i].w;
            s2 += v[i].x*v[i].x+v[i].y*v[i].y+v[i].z*v[i].z+v[i].w*v[i].w;
        }
        s1 += __shfl_xor(s1,1); s2 += __shfl_xor(s2,1);
        s1 += __shfl_xor(s1,2); s2 += __shfl_xor(s2,2);
        s1 += __shfl_xor(s1,4); s2 += __shfl_xor(s2,4);
        float mean = s1*(1.f/128.f);
        float var  = s2*(1.f/128.f) - mean*mean;
        float rstd = rsqrtf(var + 1e-5f);
        const float4* lwp = (const float4*)(lnw + j*D + g8*16);
        const float4* lbp = (const float4*)(lnb + j*D + g8*16);
        #pragma unroll
        for (int i=0;i<4;++i){
            float4 lw = lwp[i], lb = lbp[i];
            ushort4 o;
            o.x = f2bf((v[i].x-mean)*rstd*lw.x + lb.x);
            o.y = f2bf((v[i].y-mean)*rstd*lw.y + lb.y);
            o.z = f2bf((v[i].z-mean)*rstd*lw.z + lb.z);
            o.w = f2bf((v[i].w-mean)*rstd*lw.w + lb.w);
            *(ushort4*)&smHn[(32+t)*SHN + g8*16 + i*4] = o;
        }
    }
    __syncthreads();

    // ---- in_proj GEMM: M=48 (rows 32..47: halo tile, only 3 valid), N=512, K=128 ----
    {
        int w = tid>>6, lane = tid&63, q = lane>>4, r = lane&15;
        bfrag a[3][4];
        #pragma unroll
        for (int rt=0; rt<3; ++rt)
        #pragma unroll
        for (int kb=0; kb<4; ++kb)
            a[rt][kb] = *(bfrag*)&smHn[(rt*16 + r)*SHN + kb*32 + q*8];
        #pragma unroll
        for (int ct=0; ct<8; ++ct){
            int n0 = w*128 + ct*16;
            const ushort* bp = wbi + ((size_t)j*512 + n0 + r)*128 + q*8;
            facc a0 = {}, a1 = {}, a2 = {};
            #pragma unroll
            for (int kb=0; kb<4; ++kb){
                bfrag bv = *(const bfrag*)(bp + kb*32);
                a0 = MFMA(a[0][kb], bv, a0, 0,0,0);
                a1 = MFMA(a[1][kb], bv, a1, 0,0,0);
                a2 = MFMA(a[2][kb], bv, a2, 0,0,0);
            }
            int colL = n0 + r;
            if (colL < DI){
                #pragma unroll
                for (int r2=0;r2<4;++r2){
                    int rr = q*4 + r2;
                    smXm[rr*SXM + colL]      = f2bf(a0[r2]);
                    smXm[(16+rr)*SXM + colL] = f2bf(a1[r2]);
                    if (rr < 3) smXm[(32+rr)*SXM + colL] = f2bf(a2[r2]);
                }
            } else {
                int cz = colL - DI;
                #pragma unroll
                for (int r2=0;r2<4;++r2){
                    int rr = q*4 + r2;
                    z[(size_t)(base_tok + rr)*DI + cz]      = a0[r2];
                    z[(size_t)(base_tok + 16 + rr)*DI + cz] = a1[r2];
                }
            }
        }
    }
    __syncthreads();

    // ---- conv + silu (thread-per-d) ----
    {
        const float* w4 = cw + ((size_t)j*DI + tid)*4;
        float cw0=w4[0], cw1=w4[1], cw2=w4[2], cw3=w4[3];
        float cbb = cb[j*DI + tid];
        float xm1=0.f, xm2=0.f, xm3=0.f;
        if (c > 0){
            xm3 = bf2f(smXm[32*SXM + tid]);   // token -3
            xm2 = bf2f(smXm[33*SXM + tid]);   // token -2
            xm1 = bf2f(smXm[34*SXM + tid]);   // token -1
        }
        #pragma unroll 4
        for (int i=0;i<CH;++i){
            float x0 = bf2f(smXm[i*SXM + tid]);
            float v = siluf_(cbb + cw3*x0 + cw2*xm1 + cw1*xm2 + cw0*xm3);
            smXc[i*SXM + tid] = f2bf(v);
            xc[(size_t)(base_tok+i)*DI + tid] = v;
            xm3 = xm2; xm2 = xm1; xm1 = x0;
        }
    }
    __syncthreads();

    // ---- x_proj GEMM: M=32, N=64(pad40), K=256 ----
    {
        int w = tid>>6, lane = tid&63, q = lane>>4, r = lane&15;
        facc a0 = {}, a1 = {};
        const ushort* bp = wbx + ((size_t)j*64 + w*16 + r)*256 + q*8;
        #pragma unroll
        for (int kb=0; kb<8; ++kb){
            bfrag av0 = *(bfrag*)&smXc[r*SXM + kb*32 + q*8];
            bfrag av1 = *(bfrag*)&smXc[(16+r)*SXM + kb*32 + q*8];
            bfrag bv  = *(const bfrag*)(bp + kb*32);
            a0 = MFMA(av0, bv, a0, 0,0,0);
            a1 = MFMA(av1, bv, a1, 0,0,0);
        }
        int col = w*16 + r;
        #pragma unroll
        for (int r2=0;r2<4;++r2){
            int rr = q*4 + r2;
            smDbc[rr*68 + col]      = a0[r2];
            smDbc[(16+rr)*68 + col] = a1[r2];
            int row0 = base_tok + rr, row1 = base_tok + 16 + rr;
            if      (col < 8){  dtr[(size_t)row0*RK + col] = a0[r2];      dtr[(size_t)row1*RK + col] = a1[r2]; }
            else if (col < 24){ Bc [(size_t)row0*NS + (col-8)] = a0[r2];  Bc [(size_t)row1*NS + (col-8)] = a1[r2]; }
            else if (col < 40){ Cc [(size_t)row0*NS + (col-24)] = a0[r2]; Cc [(size_t)row1*NS + (col-24)] = a1[r2]; }
        }
    }
    __syncthreads();

    // ---- scan1: local chunk summary (thread-per-d) ----
    {
        float A[NS], wv[RK];
        const float* ar = A_log + ((size_t)j*DI + tid)*NS;
        #pragma unroll
        for (int n=0;n<NS;++n) A[n] = -__expf(ar[n]);
        const float* wr = Wdt + ((size_t)j*DI + tid)*RK;
        #pragma unroll
        for (int r=0;r<RK;++r) wv[r] = wr[r];
        float bb2 = bdt[j*DI + tid];
        float ap[NS], hs[NS];
        #pragma unroll
        for (int n=0;n<NS;++n){ ap[n]=1.f; hs[n]=0.f; }
        #pragma unroll 4
        for (int l=0;l<CH;++l){
            float t = bb2;
            #pragma unroll
            for (int r=0;r<RK;++r) t += smDbc[l*68+r]*wv[r];
            float dtv = softplusf_(t);
            float xv  = bf2f(smXc[l*SXM + tid]);
            float dbx = dtv*xv;
            #pragma unroll
            for (int n=0;n<NS;++n){
                float dA = __expf(dtv*A[n]);
                ap[n] *= dA;
                hs[n] = dA*hs[n] + dbx*smDbc[l*68+8+n];
            }
        }
        size_t pb = (size_t)bi*4096 + tid;
        #pragma unroll
        for (int n=0;n<NS;++n){
            Aprod[pb + (size_t)n*256] = ap[n];
            Bend [pb + (size_t)n*256] = hs[n];
        }
    }
}

// ---------------- scan mid: fold 64 chunk summaries; Bend becomes carry-in
__global__ void k_scanmid(const float* __restrict__ Aprod, float* __restrict__ Bend){
    int tid = blockIdx.x*128 + threadIdx.x;   // 16384 total
    int s = tid >> 12;
    int nd = tid & 4095;
    size_t base = (size_t)s*NCH*4096 + nd;
    float h = 0.f;
    for (int c0=0; c0<NCH; c0+=16){
        float a[16], b[16];
        #pragma unroll
        for (int i=0;i<16;++i){
            a[i] = Aprod[base + (size_t)(c0+i)*4096];
            b[i] = Bend [base + (size_t)(c0+i)*4096];
        }
        #pragma unroll
        for (int i=0;i<16;++i){
            Bend[base + (size_t)(c0+i)*4096] = h;   // carry INTO chunk c0+i
            h = a[i]*h + b[i];
        }
    }
}

// ---------------- k_tail: scan2 + gate + out_proj (CH=32)
// grid (NCH, NSTREAM), block 256
__global__ void k_tail(const float* __restrict__ dtr, const float* __restrict__ xcv,
                       const float* __restrict__ Bc, const float* __restrict__ Cc,
                       const float* __restrict__ A_log,
                       const float* __restrict__ Wdt, const float* __restrict__ bdt,
                       const float* __restrict__ h0, const float* __restrict__ z,
                       const float* __restrict__ Dp, const ushort* __restrict__ wbo,
                       float* __restrict__ cur, int blk){
    int c = blockIdx.x, s = blockIdx.y; int j = (s>>1)*3 + blk;
    int d = threadIdx.x;
    __shared__ float sB[CH*NS], sC[CH*NS], sdtr[CH*RK];
    __shared__ ushort sg[CH*SXM];
    int base_tok = s*L + c*CH;
    sB[d] = Bc[(size_t)base_tok*NS + d];
    sB[256+d] = Bc[(size_t)base_tok*NS + 256 + d];
    sC[d] = Cc[(size_t)base_tok*NS + d];
    sC[256+d] = Cc[(size_t)base_tok*NS + 256 + d];
    sdtr[d] = dtr[(size_t)base_tok*RK + d];
    float A[NS], wv[RK];
    const float* ar = A_log + ((size_t)j*DI + d)*NS;
    #pragma unroll
    for (int n=0;n<NS;++n) A[n] = -__expf(ar[n]);
    const float* wr = Wdt + ((size_t)j*DI + d)*RK;
    #pragma unroll
    for (int r=0;r<RK;++r) wv[r] = wr[r];
    float bb = bdt[j*DI + d];
    float Dpd = Dp[j*DI + d];
    float hs[NS];
    size_t pb = (size_t)(s*NCH + c)*4096 + d;
    #pragma unroll
    for (int n=0;n<NS;++n) hs[n] = h0[pb + (size_t)n*256];
    __syncthreads();
    #pragma unroll 4
    for (int l=0;l<CH;++l){
        float t = bb;
        #pragma unroll
        for (int r=0;r<RK;++r) t += sdtr[l*RK+r]*wv[r];
        float dtv = softplusf_(t);
        float xv  = xcv[(size_t)(base_tok+l)*DI + d];
        float dbx = dtv*xv;
        float p = 0.f;
        #pragma unroll
        for (int n=0;n<NS;++n){
            float dA = __expf(dtv*A[n]);
            hs[n] = dA*hs[n] + dbx*sB[l*NS+n];
            p += hs[n]*sC[l*NS+n];
        }
        float zv = z[(size_t)(base_tok+l)*DI + d];
        sg[l*SXM + d] = f2bf((p + Dpd*xv)*siluf_(zv));
    }
    __syncthreads();
    // out_proj: M=32 (2 rt), N=128; wave w -> cols [w*32, w*32+32)
    int w = d>>6, lane = d&63, q = lane>>4, r = lane&15;
    facc acc[2][2] = {};
    const ushort* b0p = wbo + ((size_t)j*128 + w*32 + r)*256 + q*8;
    const ushort* b1p = b0p + 16*256;
    #pragma unroll
    for (int kb=0; kb<8; ++kb){
        bfrag av0 = *(bfrag*)&sg[r*SXM + kb*32 + q*8];
        bfrag av1 = *(bfrag*)&sg[(16+r)*SXM + kb*32 + q*8];
        bfrag bv0 = *(const bfrag*)(b0p + kb*32);
        bfrag bv1 = *(const bfrag*)(b1p + kb*32);
        acc[0][0] = MFMA(av0,bv0,acc[0][0],0,0,0);
        acc[0][1] = MFMA(av0,bv1,acc[0][1],0,0,0);
        acc[1][0] = MFMA(av1,bv0,acc[1][0],0,0,0);
        acc[1][1] = MFMA(av1,bv1,acc[1][1],0,0,0);
    }
    #pragma unroll
    for (int rt=0; rt<2; ++rt)
    #pragma unroll
    for (int ct=0; ct<2; ++ct){
        int col = w*32 + ct*16 + r;
        #pragma unroll
        for (int r2=0;r2<4;++r2){
            int row = base_tok + rt*16 + q*4 + r2;
            cur[(size_t)row*D + col] = acc[rt][ct][r2];
        }
    }
}

// ---------------- final combine
__global__ void k_final(const float* __restrict__ cur, const float* __restrict__ res,
                        float* __restrict__ out){
    int l = blockIdx.x, b = blockIdx.y, d = threadIdx.x;
    int tf = (b*L + l)*D + d;
    int tbk = ((2+b)*L + (L-1-l))*D + d;
    float f  = cur[tf] + res[tf];
    float bw = cur[tbk] + res[tbk];
    out[((size_t)(b*D + d))*L + l] = f + bw;
    out[(size_t)2*D*L + (size_t)(b*L + l)*D + d] = res[tf];
    out[(size_t)2*D*L + (size_t)((2+b)*L + l)*D + d] = res[((2+b)*L + l)*D + d];
}

extern "C" void kernel_launch(void* const* d_in, const int* in_sizes, int n_in,
                              void* d_out, int out_size, void* d_ws, size_t ws_size,
                              hipStream_t stream){
    const float* x         = (const float*)d_in[0];
    const float* convd_w   = (const float*)d_in[1];
    const float* convd_b   = (const float*)d_in[2];
    const float* ln_w      = (const float*)d_in[3];
    const float* ln_b      = (const float*)d_in[4];
    const float* in_proj_w = (const float*)d_in[5];
    const float* conv_w    = (const float*)d_in[6];
    const float* conv_b    = (const float*)d_in[7];
    const float* xproj_w   = (const float*)d_in[8];
    const float* dtproj_w  = (const float*)d_in[9];
    const float* dtproj_b  = (const float*)d_in[10];
    const float* A_log     = (const float*)d_in[11];
    const float* Dparam    = (const float*)d_in[12];
    const float* outproj_w = (const float*)d_in[13];

    float* ws = (float*)d_ws;
    float* h     = ws; ws += SZ_D;
    float* res0  = ws; ws += SZ_D;
    float* res1  = ws; ws += SZ_D;
    float* cur   = ws; ws += SZ_D;
    float* z     = ws; ws += SZ_DI;
    float* xc    = ws; ws += SZ_DI;
    float* Aprod = ws; ws += SZ_D;   // NSTREAM*NCH*NS*DI = SZ_D
    float* Bend  = ws; ws += SZ_D;
    float* dtr   = ws; ws += (size_t)TOK*RK;
    float* Bc    = ws; ws += (size_t)TOK*NS;
    float* Cc    = ws; ws += (size_t)TOK*NS;
    ushort* wall = (ushort*)ws;
    ushort* wbd  = wall;
    ushort* wbi  = wall + 32768;
    ushort* wbo  = wall + 425984;
    ushort* wbx  = wall + 622592;

    k_cvtall<<<2816, 256, 0, stream>>>(convd_w, in_proj_w, outproj_w, xproj_w, wall);
    k_down<<<dim3(64, 2), 256, 0, stream>>>(x, wbd, convd_b, h);

    // res ping-pong: blk0 -> res0, blk1 -> res1, blk2 -> res0 (final reads res0)
    float* resin[3]  = { nullptr, res0, res1 };
    float* resout[3] = { res0,    res1, res0 };
    for (int blk = 0; blk < 3; ++blk){
        const float* ci = (blk==0) ? h : cur;
        const float* ri = (blk==0) ? h : resin[blk];
        k_head<<<NSTREAM*NCH, 256, 0, stream>>>(ci, ri, resout[blk], ln_w, ln_b, wbi, wbx,
                                                conv_w, conv_b, dtproj_w, dtproj_b, A_log,
                                                z, xc, dtr, Bc, Cc, Aprod, Bend, blk, blk==0);
        k_scanmid<<<128, 128, 0, stream>>>(Aprod, Bend);
        k_tail<<<dim3(NCH, NSTREAM), 256, 0, stream>>>(dtr, xc, Bc, Cc, A_log,
                                                       dtproj_w, dtproj_b, Bend, z,
                                                       Dparam, wbo, cur, blk);
    }

    k_final<<<dim3(L, B), 128, 0, stream>>>(cur, res0, (float*)d_out);
}